// Round 20
// baseline (34.450 us; speedup 1.0000x reference)
//
#include <hip/hip_runtime.h>
#include <math.h>

#define SD 39
#define BLOCK 1024   // 16 waves/block, ONE block per CU (prologue once/CU)

typedef _Float16 half8 __attribute__((ext_vector_type(8)));
typedef float f32x4 __attribute__((ext_vector_type(4)));

// ---- LDS layout (dword offsets); per-lane MFMA fragments (see R14/R15).
#define DW_AW1 0      // 8 frags  (mt0..3 x ks0..1)   k = ks*32 + 8g + j ; 0 if k>=39
#define DW_AB1 2048   // 4 frags  f32x4 bias: eb1[mt*16+4g+r]
#define DW_AW2 3072   // 4 frags  (mt0..1 x ks0..1)   o1 = ks*32+16*(j>>2)+4g+(j&3)
#define DW_AB2 4096   // 2 frags  eb2[mt*16+4g+r]
#define DW_AW3 4608   // 1 frag   c<4: ew3[c][o2], o2=16*(j>>2)+4g+(j&3); else 0
#define DW_AB3 4864   // 1 frag   g==0 ? eb3[r] : 0
#define DW_AD1 5120   // 2 frags  (g==0&&j<4) ? dw1[(mt*16+c)*4+j] : 0
#define DW_AE1 5632   // 2 frags  db1[mt*16+4g+r]
#define DW_AD2 6144   // 1 frag   dw2[c*32 + 16*(j>>2)+4g+(j&3)]
#define DW_AE2 6400   // 1 frag   db2[4g+r]
#define DW_AD3 6656   // 1 frag   (c<8&&j<4) ? dw3[c*16+4g+j] : 0
#define DW_AE3 6912   // 1 frag   (4g+r<8) ? db3[4g+r] : 0
#define DW_QPE 7168   // qp[0,2,4,6]
#define DW_TOT 7172   // dwords = 28688 B LDS

// Issue one tile's raw state loads (no conversion -> loads stay in flight).
#define LOAD_MAIN(R, S0, S1)                                               \
    {                                                                      \
        const float* sp = state + ((R) + c) * SD;                          \
        S0 = *(const float4*)(sp + 8 * g);                                 \
        S1 = *(const float4*)(sp + 8 * g + 4);                             \
    }
#define LOAD_TAIL(R, S2, S3)                                               \
    {                                                                      \
        S2 = make_float4(0.f, 0.f, 0.f, 0.f);                              \
        S3 = make_float4(0.f, 0.f, 0.f, 0.f);                              \
        if (g == 0) {                                                      \
            const float* sp = state + ((R) + c) * SD;                      \
            S2 = *(const float4*)(sp + 32);                                \
            S3 = *(const float4*)(sp + 35);                                \
        }                                                                  \
    }
#define CONV(S0, S1, S2, S3, X0, X1)                                       \
    {                                                                      \
        X0[0] = (_Float16)S0.x; X0[1] = (_Float16)S0.y;                    \
        X0[2] = (_Float16)S0.z; X0[3] = (_Float16)S0.w;                    \
        X0[4] = (_Float16)S1.x; X0[5] = (_Float16)S1.y;                    \
        X0[6] = (_Float16)S1.z; X0[7] = (_Float16)S1.w;                    \
        X1[0] = (_Float16)S2.x; X1[1] = (_Float16)S2.y;                    \
        X1[2] = (_Float16)S2.z; X1[3] = (_Float16)S2.w;                    \
        X1[4] = (_Float16)S3.y; X1[5] = (_Float16)S3.z;                    \
        X1[6] = (_Float16)S3.w; X1[7] = (_Float16)0.0f;                    \
    }

__device__ __forceinline__ void compute_pair(
    const half8* hws, const f32x4* fws, const float* qpep,
    int lane, int g, int c,
    half8 x0a, half8 x1a, half8 x0b, half8 x1b,
    long long RA, long long RB, float* __restrict__ out)
{
    // ---- L1: 4 M-tiles x 2 K-steps ----
    f32x4 c1a[4], c1b[4];
    #pragma unroll
    for (int mt = 0; mt < 4; mt++) {
        half8 w0 = hws[DW_AW1 / 4 + (mt * 2 + 0) * 64 + lane];
        half8 w1 = hws[DW_AW1 / 4 + (mt * 2 + 1) * 64 + lane];
        f32x4 bias = fws[DW_AB1 / 4 + mt * 64 + lane];
        f32x4 ta = __builtin_amdgcn_mfma_f32_16x16x32_f16(w0, x0a, bias, 0, 0, 0);
        f32x4 tb = __builtin_amdgcn_mfma_f32_16x16x32_f16(w0, x0b, bias, 0, 0, 0);
        c1a[mt] = __builtin_amdgcn_mfma_f32_16x16x32_f16(w1, x1a, ta, 0, 0, 0);
        c1b[mt] = __builtin_amdgcn_mfma_f32_16x16x32_f16(w1, x1b, tb, 0, 0, 0);
    }
    half8 hb0a, hb1a, hb0b, hb1b;
    #pragma unroll
    for (int j = 0; j < 8; j++) {
        hb0a[j] = (_Float16)fmaxf(c1a[j >> 2][j & 3], 0.0f);
        hb1a[j] = (_Float16)fmaxf(c1a[2 + (j >> 2)][j & 3], 0.0f);
        hb0b[j] = (_Float16)fmaxf(c1b[j >> 2][j & 3], 0.0f);
        hb1b[j] = (_Float16)fmaxf(c1b[2 + (j >> 2)][j & 3], 0.0f);
    }

    // ---- L2: 2 M-tiles x 2 K-steps ----
    f32x4 c2a[2], c2b[2];
    #pragma unroll
    for (int mt = 0; mt < 2; mt++) {
        half8 w0 = hws[DW_AW2 / 4 + (mt * 2 + 0) * 64 + lane];
        half8 w1 = hws[DW_AW2 / 4 + (mt * 2 + 1) * 64 + lane];
        f32x4 bias = fws[DW_AB2 / 4 + mt * 64 + lane];
        f32x4 ta = __builtin_amdgcn_mfma_f32_16x16x32_f16(w0, hb0a, bias, 0, 0, 0);
        f32x4 tb = __builtin_amdgcn_mfma_f32_16x16x32_f16(w0, hb0b, bias, 0, 0, 0);
        c2a[mt] = __builtin_amdgcn_mfma_f32_16x16x32_f16(w1, hb1a, ta, 0, 0, 0);
        c2b[mt] = __builtin_amdgcn_mfma_f32_16x16x32_f16(w1, hb1b, tb, 0, 0, 0);
    }
    half8 hb2a, hb2b;
    #pragma unroll
    for (int j = 0; j < 8; j++) {
        hb2a[j] = (_Float16)fmaxf(c2a[j >> 2][j & 3], 0.0f);
        hb2b[j] = (_Float16)fmaxf(c2b[j >> 2][j & 3], 0.0f);
    }

    // ---- L3 ----
    half8 w3 = hws[DW_AW3 / 4 + lane];
    f32x4 b3 = fws[DW_AB3 / 4 + lane];
    f32x4 ea = __builtin_amdgcn_mfma_f32_16x16x32_f16(w3, hb2a, b3, 0, 0, 0);
    f32x4 eb = __builtin_amdgcn_mfma_f32_16x16x32_f16(w3, hb2b, b3, 0, 0, 0);

    // ---- quantum: ev_i = prod_{j<=i} cos(tanh(e_j)*pi + qp[2j]) ----
    // (RZ cancels under Z-measure; CNOT chain -> bit i = b0^..^bi)
    float eva[4], evb4[4]; float cpa = 1.0f, cpb = 1.0f;
    #pragma unroll
    for (int r = 0; r < 4; r++) {
        float exa = __expf(2.0f * ea[r]);
        float exb = __expf(2.0f * eb[r]);
        float ta = 1.0f - 2.0f / (exa + 1.0f);     // tanh(x)
        float tb = 1.0f - 2.0f / (exb + 1.0f);
        float qpe = qpep[r];
        cpa *= __cosf(fmaf(ta, 3.14159265358979323846f, qpe));
        cpb *= __cosf(fmaf(tb, 3.14159265358979323846f, qpe));
        eva[r] = cpa; evb4[r] = cpb;
    }
    half8 evfa, evfb;
    #pragma unroll
    for (int j = 0; j < 8; j++) {
        evfa[j] = (j < 4) ? (_Float16)eva[j] : (_Float16)0.0f;
        evfb[j] = (j < 4) ? (_Float16)evb4[j] : (_Float16)0.0f;
    }

    // ---- D1: 2 M-tiles ----
    f32x4 d1a[2], d1b[2];
    #pragma unroll
    for (int mt = 0; mt < 2; mt++) {
        half8 wd = hws[DW_AD1 / 4 + mt * 64 + lane];
        f32x4 be = fws[DW_AE1 / 4 + mt * 64 + lane];
        d1a[mt] = __builtin_amdgcn_mfma_f32_16x16x32_f16(wd, evfa, be, 0, 0, 0);
        d1b[mt] = __builtin_amdgcn_mfma_f32_16x16x32_f16(wd, evfb, be, 0, 0, 0);
    }
    half8 dba, dbb;
    #pragma unroll
    for (int j = 0; j < 8; j++) {
        dba[j] = (_Float16)fmaxf(d1a[j >> 2][j & 3], 0.0f);
        dbb[j] = (_Float16)fmaxf(d1b[j >> 2][j & 3], 0.0f);
    }

    // ---- D2 ----
    half8 wd2 = hws[DW_AD2 / 4 + lane];
    f32x4 be2 = fws[DW_AE2 / 4 + lane];
    f32x4 d2a = __builtin_amdgcn_mfma_f32_16x16x32_f16(wd2, dba, be2, 0, 0, 0);
    f32x4 d2b = __builtin_amdgcn_mfma_f32_16x16x32_f16(wd2, dbb, be2, 0, 0, 0);
    half8 d2fa, d2fb;
    #pragma unroll
    for (int j = 0; j < 8; j++) {
        d2fa[j] = (j < 4) ? (_Float16)fmaxf(d2a[j], 0.0f) : (_Float16)0.0f;
        d2fb[j] = (j < 4) ? (_Float16)fmaxf(d2b[j], 0.0f) : (_Float16)0.0f;
    }

    // ---- D3 + stores ----
    half8 wd3 = hws[DW_AD3 / 4 + lane];
    f32x4 be3 = fws[DW_AE3 / 4 + lane];
    f32x4 oa = __builtin_amdgcn_mfma_f32_16x16x32_f16(wd3, d2fa, be3, 0, 0, 0);
    f32x4 ob = __builtin_amdgcn_mfma_f32_16x16x32_f16(wd3, d2fb, be3, 0, 0, 0);

    if (lane < 32) {
        float4* opa = (float4*)(out + (RA + c) * 8 + 4 * g);
        *opa = make_float4(oa[0], oa[1], oa[2], oa[3]);
        float4* opb = (float4*)(out + (RB + c) * 8 + 4 * g);
        *opb = make_float4(ob[0], ob[1], ob[2], ob[3]);
    }
}

__global__ __launch_bounds__(BLOCK)
__attribute__((amdgpu_waves_per_eu(4)))
void qnet_kernel(const float* __restrict__ state,
                 const float* __restrict__ ew1, const float* __restrict__ eb1,
                 const float* __restrict__ ew2, const float* __restrict__ eb2,
                 const float* __restrict__ ew3, const float* __restrict__ eb3,
                 const float* __restrict__ qp,
                 const float* __restrict__ dw1, const float* __restrict__ db1,
                 const float* __restrict__ dw2, const float* __restrict__ db2,
                 const float* __restrict__ dw3, const float* __restrict__ db3,
                 float* __restrict__ out, int ntiles)
{
    __shared__ __align__(16) float lf[DW_TOT];
    _Float16* wh = (_Float16*)lf;
    const int tid = threadIdx.x;

    // ---- fragment build (once per CU) ----
    for (int i = tid; i < 8 * 512; i += BLOCK) {          // AW1
        int frag = i >> 9, lane = (i >> 3) & 63, j = i & 7;
        int mt = frag >> 1, ks = frag & 1, g = lane >> 4, c = lane & 15;
        int m = mt * 16 + c, k = ks * 32 + 8 * g + j;
        wh[DW_AW1 * 2 + i] = (k < SD) ? (_Float16)ew1[m * SD + k] : (_Float16)0.0f;
    }
    for (int i = tid; i < 4 * 512; i += BLOCK) {          // AW2
        int frag = i >> 9, lane = (i >> 3) & 63, j = i & 7;
        int mt = frag >> 1, ks = frag & 1, g = lane >> 4, c = lane & 15;
        int m = mt * 16 + c, o1 = ks * 32 + 16 * (j >> 2) + 4 * g + (j & 3);
        wh[DW_AW2 * 2 + i] = (_Float16)ew2[m * 64 + o1];
    }
    for (int i = tid; i < 512; i += BLOCK) {              // AW3
        int lane = (i >> 3) & 63, j = i & 7, g = lane >> 4, c = lane & 15;
        int o2 = 16 * (j >> 2) + 4 * g + (j & 3);
        wh[DW_AW3 * 2 + i] = (c < 4) ? (_Float16)ew3[c * 32 + o2] : (_Float16)0.0f;
    }
    for (int i = tid; i < 2 * 512; i += BLOCK) {          // AD1
        int frag = i >> 9, lane = (i >> 3) & 63, j = i & 7;
        int g = lane >> 4, c = lane & 15, m = frag * 16 + c;
        wh[DW_AD1 * 2 + i] = (g == 0 && j < 4) ? (_Float16)dw1[m * 4 + j]
                                               : (_Float16)0.0f;
    }
    for (int i = tid; i < 512; i += BLOCK) {              // AD2
        int lane = (i >> 3) & 63, j = i & 7, g = lane >> 4, c = lane & 15;
        int k1 = 16 * (j >> 2) + 4 * g + (j & 3);
        wh[DW_AD2 * 2 + i] = (_Float16)dw2[c * 32 + k1];
    }
    for (int i = tid; i < 512; i += BLOCK) {              // AD3
        int lane = (i >> 3) & 63, j = i & 7, g = lane >> 4, c = lane & 15;
        wh[DW_AD3 * 2 + i] = (c < 8 && j < 4) ? (_Float16)dw3[c * 16 + 4 * g + j]
                                              : (_Float16)0.0f;
    }
    for (int i = tid; i < 1024; i += BLOCK) {             // AB1
        int mt = i >> 8, lane = (i >> 2) & 63, r = i & 3, g = lane >> 4;
        lf[DW_AB1 + i] = eb1[mt * 16 + 4 * g + r];
    }
    for (int i = tid; i < 512; i += BLOCK) {              // AB2
        int mt = i >> 8, lane = (i >> 2) & 63, r = i & 3, g = lane >> 4;
        lf[DW_AB2 + i] = eb2[mt * 16 + 4 * g + r];
    }
    for (int i = tid; i < 256; i += BLOCK) {              // AB3
        int lane = (i >> 2) & 63, r = i & 3, g = lane >> 4;
        lf[DW_AB3 + i] = (g == 0) ? eb3[r] : 0.0f;
    }
    for (int i = tid; i < 512; i += BLOCK) {              // AE1
        int mt = i >> 8, lane = (i >> 2) & 63, r = i & 3, g = lane >> 4;
        lf[DW_AE1 + i] = db1[mt * 16 + 4 * g + r];
    }
    for (int i = tid; i < 256; i += BLOCK) {              // AE2
        int lane = (i >> 2) & 63, r = i & 3, g = lane >> 4;
        lf[DW_AE2 + i] = db2[4 * g + r];
    }
    for (int i = tid; i < 256; i += BLOCK) {              // AE3
        int lane = (i >> 2) & 63, r = i & 3, g = lane >> 4;
        lf[DW_AE3 + i] = (4 * g + r < 8) ? db3[4 * g + r] : 0.0f;
    }
    for (int i = tid; i < 4; i += BLOCK) lf[DW_QPE + i] = qp[2 * i];
    __syncthreads();

    const int lane = tid & 63;
    const int g = lane >> 4, c = lane & 15;
    const int gwave = blockIdx.x * (BLOCK / 64) + (tid >> 6);

    const half8* hws = (const half8*)lf;
    const f32x4* fws = (const f32x4*)lf;
    const float* qpep = lf + DW_QPE;

    const long long t0 = 4LL * gwave;
    if (t0 + 4 <= ntiles) {
        // FAST PATH: issue ALL 4 tiles' state loads up front; pair CD's loads
        // complete for free under pair AB's ~2500-cycle compute (counted
        // vmcnt lets AB start as soon as its own loads land).
        const long long RA = t0 * 16, RB = RA + 16, RC = RA + 32, RD = RA + 48;
        float4 A0, A1, A2, A3, B0, B1, B2, B3;
        float4 C0, C1, C2, C3, D0, D1, D2, D3;
        LOAD_MAIN(RA, A0, A1) LOAD_MAIN(RB, B0, B1)
        LOAD_MAIN(RC, C0, C1) LOAD_MAIN(RD, D0, D1)
        LOAD_TAIL(RA, A2, A3) LOAD_TAIL(RB, B2, B3)
        LOAD_TAIL(RC, C2, C3) LOAD_TAIL(RD, D2, D3)

        half8 x0a, x1a, x0b, x1b;
        CONV(A0, A1, A2, A3, x0a, x1a)
        CONV(B0, B1, B2, B3, x0b, x1b)
        compute_pair(hws, fws, qpep, lane, g, c, x0a, x1a, x0b, x1b, RA, RB, out);

        CONV(C0, C1, C2, C3, x0a, x1a)
        CONV(D0, D1, D2, D3, x0b, x1b)
        compute_pair(hws, fws, qpep, lane, g, c, x0a, x1a, x0b, x1b, RC, RD, out);
    } else {
        // tail path (not hit at B=262144): per-pair
        for (long long p = t0; p + 1 < ntiles; p += 2) {
            const long long RA = p * 16, RB = RA + 16;
            float4 A0, A1, A2, A3, B0, B1, B2, B3;
            LOAD_MAIN(RA, A0, A1) LOAD_MAIN(RB, B0, B1)
            LOAD_TAIL(RA, A2, A3) LOAD_TAIL(RB, B2, B3)
            half8 x0a, x1a, x0b, x1b;
            CONV(A0, A1, A2, A3, x0a, x1a)
            CONV(B0, B1, B2, B3, x0b, x1b)
            compute_pair(hws, fws, qpep, lane, g, c, x0a, x1a, x0b, x1b, RA, RB, out);
        }
    }
}

extern "C" void kernel_launch(void* const* d_in, const int* in_sizes, int n_in,
                              void* d_out, int out_size, void* d_ws, size_t ws_size,
                              hipStream_t stream) {
    const float* state = (const float*)d_in[0];
    const float* ew1 = (const float*)d_in[1];
    const float* eb1 = (const float*)d_in[2];
    const float* ew2 = (const float*)d_in[3];
    const float* eb2 = (const float*)d_in[4];
    const float* ew3 = (const float*)d_in[5];
    const float* eb3 = (const float*)d_in[6];
    const float* qp  = (const float*)d_in[7];
    const float* dw1 = (const float*)d_in[8];
    const float* db1 = (const float*)d_in[9];
    const float* dw2 = (const float*)d_in[10];
    const float* db2 = (const float*)d_in[11];
    const float* dw3 = (const float*)d_in[12];
    const float* db3 = (const float*)d_in[13];
    float* out = (float*)d_out;

    const int B = in_sizes[0] / SD;
    const int ntiles = B / 16;                    // 262144 -> 16384

    // 256 blocks x 16 waves = 4096 waves, 4 tiles/wave, 1 block/CU.
    hipLaunchKernelGGL(qnet_kernel, dim3(256), dim3(BLOCK), 0, stream,
                       state, ew1, eb1, ew2, eb2, ew3, eb3, qp,
                       dw1, db1, dw2, db2, dw3, db3, out, ntiles);
}

// Round 21
// 19.464 us; speedup vs baseline: 1.7700x; 1.7700x over previous
//
#include <hip/hip_runtime.h>
#include <math.h>

#define SD 39
#define BLOCK 1024   // 16 waves/block; TWO blocks per CU -> 32 waves/CU
                     // = 8 waves/SIMD (kernel is 64 VGPR per R20 counters;
                     // R19's 1 block/CU left occupancy grid-limited at 4).

typedef _Float16 half8 __attribute__((ext_vector_type(8)));
typedef float f32x4 __attribute__((ext_vector_type(4)));

// ---- LDS layout (dword offsets); per-lane MFMA fragments (see R14/R15).
#define DW_AW1 0      // 8 frags  (mt0..3 x ks0..1)   k = ks*32 + 8g + j ; 0 if k>=39
#define DW_AB1 2048   // 4 frags  f32x4 bias: eb1[mt*16+4g+r]
#define DW_AW2 3072   // 4 frags  (mt0..1 x ks0..1)   o1 = ks*32+16*(j>>2)+4g+(j&3)
#define DW_AB2 4096   // 2 frags  eb2[mt*16+4g+r]
#define DW_AW3 4608   // 1 frag   c<4: ew3[c][o2], o2=16*(j>>2)+4g+(j&3); else 0
#define DW_AB3 4864   // 1 frag   g==0 ? eb3[r] : 0
#define DW_AD1 5120   // 2 frags  (g==0&&j<4) ? dw1[(mt*16+c)*4+j] : 0
#define DW_AE1 5632   // 2 frags  db1[mt*16+4g+r]
#define DW_AD2 6144   // 1 frag   dw2[c*32 + 16*(j>>2)+4g+(j&3)]
#define DW_AE2 6400   // 1 frag   db2[4g+r]
#define DW_AD3 6656   // 1 frag   (c<8&&j<4) ? dw3[c*16+4g+j] : 0
#define DW_AE3 6912   // 1 frag   (4g+r<8) ? db3[4g+r] : 0
#define DW_QPE 7168   // qp[0,2,4,6]
#define DW_TOT 7172   // dwords = 28688 B LDS (2 images/CU at 2 blocks/CU)

// Load one tile's state B-fragments (rows R..R+15, lane c owns row R+c).
#define LOAD_STATE(R, X0, X1)                                              \
    {                                                                      \
        const float* sp = state + ((R) + c) * SD;                          \
        float4 s0 = *(const float4*)(sp + 8 * g);                          \
        float4 s1 = *(const float4*)(sp + 8 * g + 4);                      \
        float4 s2 = make_float4(0.f, 0.f, 0.f, 0.f);                       \
        float4 s3 = make_float4(0.f, 0.f, 0.f, 0.f);                       \
        if (g == 0) {                                                      \
            s2 = *(const float4*)(sp + 32);                                \
            s3 = *(const float4*)(sp + 35);                                \
        }                                                                  \
        X0[0] = (_Float16)s0.x; X0[1] = (_Float16)s0.y;                    \
        X0[2] = (_Float16)s0.z; X0[3] = (_Float16)s0.w;                    \
        X0[4] = (_Float16)s1.x; X0[5] = (_Float16)s1.y;                    \
        X0[6] = (_Float16)s1.z; X0[7] = (_Float16)s1.w;                    \
        X1[0] = (_Float16)s2.x; X1[1] = (_Float16)s2.y;                    \
        X1[2] = (_Float16)s2.z; X1[3] = (_Float16)s2.w;                    \
        X1[4] = (_Float16)s3.y; X1[5] = (_Float16)s3.z;                    \
        X1[6] = (_Float16)s3.w; X1[7] = (_Float16)0.0f;                    \
    }

__global__ __launch_bounds__(BLOCK)
__attribute__((amdgpu_waves_per_eu(4)))
void qnet_kernel(const float* __restrict__ state,
                 const float* __restrict__ ew1, const float* __restrict__ eb1,
                 const float* __restrict__ ew2, const float* __restrict__ eb2,
                 const float* __restrict__ ew3, const float* __restrict__ eb3,
                 const float* __restrict__ qp,
                 const float* __restrict__ dw1, const float* __restrict__ db1,
                 const float* __restrict__ dw2, const float* __restrict__ db2,
                 const float* __restrict__ dw3, const float* __restrict__ db3,
                 float* __restrict__ out, int ntiles)
{
    __shared__ __align__(16) float lf[DW_TOT];
    _Float16* wh = (_Float16*)lf;
    const int tid = threadIdx.x;

    // ---- fragment build (twice per CU at 2 blocks/CU; ~1us, overlapped) ----
    for (int i = tid; i < 8 * 512; i += BLOCK) {          // AW1
        int frag = i >> 9, lane = (i >> 3) & 63, j = i & 7;
        int mt = frag >> 1, ks = frag & 1, g = lane >> 4, c = lane & 15;
        int m = mt * 16 + c, k = ks * 32 + 8 * g + j;
        wh[DW_AW1 * 2 + i] = (k < SD) ? (_Float16)ew1[m * SD + k] : (_Float16)0.0f;
    }
    for (int i = tid; i < 4 * 512; i += BLOCK) {          // AW2
        int frag = i >> 9, lane = (i >> 3) & 63, j = i & 7;
        int mt = frag >> 1, ks = frag & 1, g = lane >> 4, c = lane & 15;
        int m = mt * 16 + c, o1 = ks * 32 + 16 * (j >> 2) + 4 * g + (j & 3);
        wh[DW_AW2 * 2 + i] = (_Float16)ew2[m * 64 + o1];
    }
    for (int i = tid; i < 512; i += BLOCK) {              // AW3
        int lane = (i >> 3) & 63, j = i & 7, g = lane >> 4, c = lane & 15;
        int o2 = 16 * (j >> 2) + 4 * g + (j & 3);
        wh[DW_AW3 * 2 + i] = (c < 4) ? (_Float16)ew3[c * 32 + o2] : (_Float16)0.0f;
    }
    for (int i = tid; i < 2 * 512; i += BLOCK) {          // AD1
        int frag = i >> 9, lane = (i >> 3) & 63, j = i & 7;
        int g = lane >> 4, c = lane & 15, m = frag * 16 + c;
        wh[DW_AD1 * 2 + i] = (g == 0 && j < 4) ? (_Float16)dw1[m * 4 + j]
                                               : (_Float16)0.0f;
    }
    for (int i = tid; i < 512; i += BLOCK) {              // AD2
        int lane = (i >> 3) & 63, j = i & 7, g = lane >> 4, c = lane & 15;
        int k1 = 16 * (j >> 2) + 4 * g + (j & 3);
        wh[DW_AD2 * 2 + i] = (_Float16)dw2[c * 32 + k1];
    }
    for (int i = tid; i < 512; i += BLOCK) {              // AD3
        int lane = (i >> 3) & 63, j = i & 7, g = lane >> 4, c = lane & 15;
        wh[DW_AD3 * 2 + i] = (c < 8 && j < 4) ? (_Float16)dw3[c * 16 + 4 * g + j]
                                              : (_Float16)0.0f;
    }
    for (int i = tid; i < 1024; i += BLOCK) {             // AB1
        int mt = i >> 8, lane = (i >> 2) & 63, r = i & 3, g = lane >> 4;
        lf[DW_AB1 + i] = eb1[mt * 16 + 4 * g + r];
    }
    for (int i = tid; i < 512; i += BLOCK) {              // AB2
        int mt = i >> 8, lane = (i >> 2) & 63, r = i & 3, g = lane >> 4;
        lf[DW_AB2 + i] = eb2[mt * 16 + 4 * g + r];
    }
    for (int i = tid; i < 256; i += BLOCK) {              // AB3
        int lane = (i >> 2) & 63, r = i & 3, g = lane >> 4;
        lf[DW_AB3 + i] = (g == 0) ? eb3[r] : 0.0f;
    }
    for (int i = tid; i < 512; i += BLOCK) {              // AE1
        int mt = i >> 8, lane = (i >> 2) & 63, r = i & 3, g = lane >> 4;
        lf[DW_AE1 + i] = db1[mt * 16 + 4 * g + r];
    }
    for (int i = tid; i < 256; i += BLOCK) {              // AE2
        int lane = (i >> 2) & 63, r = i & 3, g = lane >> 4;
        lf[DW_AE2 + i] = db2[4 * g + r];
    }
    for (int i = tid; i < 256; i += BLOCK) {              // AE3
        int lane = (i >> 2) & 63, r = i & 3, g = lane >> 4;
        lf[DW_AE3 + i] = (4 * g + r < 8) ? db3[4 * g + r] : 0.0f;
    }
    for (int i = tid; i < 4; i += BLOCK) lf[DW_QPE + i] = qp[2 * i];
    __syncthreads();

    const int lane = tid & 63;
    const int g = lane >> 4, c = lane & 15;
    const int gwave = blockIdx.x * (BLOCK / 64) + (tid >> 6);

    const half8* hws = (const half8*)lf;
    const f32x4* fws = (const f32x4*)lf;
    const float* qpep = lf + DW_QPE;

    // ONE pair (2 tiles) per wave: 8192 waves x 2 = 16384 tiles.
    const long long p = gwave;
    if (2 * p + 1 < (long long)ntiles) {
        const long long RA = 2 * p * 16;
        const long long RB = RA + 16;

        half8 x0a, x1a, x0b, x1b;
        LOAD_STATE(RA, x0a, x1a)
        LOAD_STATE(RB, x0b, x1b)

        // ---- L1: 4 M-tiles x 2 K-steps ----
        f32x4 c1a[4], c1b[4];
        #pragma unroll
        for (int mt = 0; mt < 4; mt++) {
            half8 w0 = hws[DW_AW1 / 4 + (mt * 2 + 0) * 64 + lane];
            half8 w1 = hws[DW_AW1 / 4 + (mt * 2 + 1) * 64 + lane];
            f32x4 bias = fws[DW_AB1 / 4 + mt * 64 + lane];
            f32x4 ta = __builtin_amdgcn_mfma_f32_16x16x32_f16(w0, x0a, bias, 0, 0, 0);
            f32x4 tb = __builtin_amdgcn_mfma_f32_16x16x32_f16(w0, x0b, bias, 0, 0, 0);
            c1a[mt] = __builtin_amdgcn_mfma_f32_16x16x32_f16(w1, x1a, ta, 0, 0, 0);
            c1b[mt] = __builtin_amdgcn_mfma_f32_16x16x32_f16(w1, x1b, tb, 0, 0, 0);
        }
        half8 hb0a, hb1a, hb0b, hb1b;
        #pragma unroll
        for (int j = 0; j < 8; j++) {
            hb0a[j] = (_Float16)fmaxf(c1a[j >> 2][j & 3], 0.0f);
            hb1a[j] = (_Float16)fmaxf(c1a[2 + (j >> 2)][j & 3], 0.0f);
            hb0b[j] = (_Float16)fmaxf(c1b[j >> 2][j & 3], 0.0f);
            hb1b[j] = (_Float16)fmaxf(c1b[2 + (j >> 2)][j & 3], 0.0f);
        }

        // ---- L2: 2 M-tiles x 2 K-steps ----
        f32x4 c2a[2], c2b[2];
        #pragma unroll
        for (int mt = 0; mt < 2; mt++) {
            half8 w0 = hws[DW_AW2 / 4 + (mt * 2 + 0) * 64 + lane];
            half8 w1 = hws[DW_AW2 / 4 + (mt * 2 + 1) * 64 + lane];
            f32x4 bias = fws[DW_AB2 / 4 + mt * 64 + lane];
            f32x4 ta = __builtin_amdgcn_mfma_f32_16x16x32_f16(w0, hb0a, bias, 0, 0, 0);
            f32x4 tb = __builtin_amdgcn_mfma_f32_16x16x32_f16(w0, hb0b, bias, 0, 0, 0);
            c2a[mt] = __builtin_amdgcn_mfma_f32_16x16x32_f16(w1, hb1a, ta, 0, 0, 0);
            c2b[mt] = __builtin_amdgcn_mfma_f32_16x16x32_f16(w1, hb1b, tb, 0, 0, 0);
        }
        half8 hb2a, hb2b;
        #pragma unroll
        for (int j = 0; j < 8; j++) {
            hb2a[j] = (_Float16)fmaxf(c2a[j >> 2][j & 3], 0.0f);
            hb2b[j] = (_Float16)fmaxf(c2b[j >> 2][j & 3], 0.0f);
        }

        // ---- L3 ----
        half8 w3 = hws[DW_AW3 / 4 + lane];
        f32x4 b3 = fws[DW_AB3 / 4 + lane];
        f32x4 ea = __builtin_amdgcn_mfma_f32_16x16x32_f16(w3, hb2a, b3, 0, 0, 0);
        f32x4 eb = __builtin_amdgcn_mfma_f32_16x16x32_f16(w3, hb2b, b3, 0, 0, 0);

        // ---- quantum: ev_i = prod_{j<=i} cos(tanh(e_j)*pi + qp[2j]) ----
        // (RZ cancels under Z-measure; CNOT chain -> bit i = b0^..^bi)
        float eva[4], evb4[4]; float cpa = 1.0f, cpb = 1.0f;
        #pragma unroll
        for (int r = 0; r < 4; r++) {
            float exa = __expf(2.0f * ea[r]);
            float exb = __expf(2.0f * eb[r]);
            float ta = 1.0f - 2.0f / (exa + 1.0f);     // tanh(x)
            float tb = 1.0f - 2.0f / (exb + 1.0f);
            float qpe = qpep[r];
            cpa *= __cosf(fmaf(ta, 3.14159265358979323846f, qpe));
            cpb *= __cosf(fmaf(tb, 3.14159265358979323846f, qpe));
            eva[r] = cpa; evb4[r] = cpb;
        }
        half8 evfa, evfb;
        #pragma unroll
        for (int j = 0; j < 8; j++) {
            evfa[j] = (j < 4) ? (_Float16)eva[j] : (_Float16)0.0f;
            evfb[j] = (j < 4) ? (_Float16)evb4[j] : (_Float16)0.0f;
        }

        // ---- D1: 2 M-tiles ----
        f32x4 d1a[2], d1b[2];
        #pragma unroll
        for (int mt = 0; mt < 2; mt++) {
            half8 wd = hws[DW_AD1 / 4 + mt * 64 + lane];
            f32x4 be = fws[DW_AE1 / 4 + mt * 64 + lane];
            d1a[mt] = __builtin_amdgcn_mfma_f32_16x16x32_f16(wd, evfa, be, 0, 0, 0);
            d1b[mt] = __builtin_amdgcn_mfma_f32_16x16x32_f16(wd, evfb, be, 0, 0, 0);
        }
        half8 dba, dbb;
        #pragma unroll
        for (int j = 0; j < 8; j++) {
            dba[j] = (_Float16)fmaxf(d1a[j >> 2][j & 3], 0.0f);
            dbb[j] = (_Float16)fmaxf(d1b[j >> 2][j & 3], 0.0f);
        }

        // ---- D2 ----
        half8 wd2 = hws[DW_AD2 / 4 + lane];
        f32x4 be2 = fws[DW_AE2 / 4 + lane];
        f32x4 d2a = __builtin_amdgcn_mfma_f32_16x16x32_f16(wd2, dba, be2, 0, 0, 0);
        f32x4 d2b = __builtin_amdgcn_mfma_f32_16x16x32_f16(wd2, dbb, be2, 0, 0, 0);
        half8 d2fa, d2fb;
        #pragma unroll
        for (int j = 0; j < 8; j++) {
            d2fa[j] = (j < 4) ? (_Float16)fmaxf(d2a[j], 0.0f) : (_Float16)0.0f;
            d2fb[j] = (j < 4) ? (_Float16)fmaxf(d2b[j], 0.0f) : (_Float16)0.0f;
        }

        // ---- D3 + stores ----
        half8 wd3 = hws[DW_AD3 / 4 + lane];
        f32x4 be3 = fws[DW_AE3 / 4 + lane];
        f32x4 oa = __builtin_amdgcn_mfma_f32_16x16x32_f16(wd3, d2fa, be3, 0, 0, 0);
        f32x4 ob = __builtin_amdgcn_mfma_f32_16x16x32_f16(wd3, d2fb, be3, 0, 0, 0);

        if (lane < 32) {
            float4* opa = (float4*)(out + (RA + c) * 8 + 4 * g);
            *opa = make_float4(oa[0], oa[1], oa[2], oa[3]);
            float4* opb = (float4*)(out + (RB + c) * 8 + 4 * g);
            *opb = make_float4(ob[0], ob[1], ob[2], ob[3]);
        }
    }
}

extern "C" void kernel_launch(void* const* d_in, const int* in_sizes, int n_in,
                              void* d_out, int out_size, void* d_ws, size_t ws_size,
                              hipStream_t stream) {
    const float* state = (const float*)d_in[0];
    const float* ew1 = (const float*)d_in[1];
    const float* eb1 = (const float*)d_in[2];
    const float* ew2 = (const float*)d_in[3];
    const float* eb2 = (const float*)d_in[4];
    const float* ew3 = (const float*)d_in[5];
    const float* eb3 = (const float*)d_in[6];
    const float* qp  = (const float*)d_in[7];
    const float* dw1 = (const float*)d_in[8];
    const float* db1 = (const float*)d_in[9];
    const float* dw2 = (const float*)d_in[10];
    const float* db2 = (const float*)d_in[11];
    const float* dw3 = (const float*)d_in[12];
    const float* db3 = (const float*)d_in[13];
    float* out = (float*)d_out;

    const int B = in_sizes[0] / SD;
    const int ntiles = B / 16;                    // 262144 -> 16384

    // 512 blocks x 16 waves = 8192 waves, 1 pair (2 tiles) per wave;
    // 2 blocks/CU -> 32 waves/CU = 8 waves/SIMD (64-VGPR kernel per R20).
    hipLaunchKernelGGL(qnet_kernel, dim3(512), dim3(BLOCK), 0, stream,
                       state, ew1, eb1, ew2, eb2, ew3, eb3, qp,
                       dw1, db1, dw2, db2, dw3, db3, out, ntiles);
}

// Round 22
// 17.369 us; speedup vs baseline: 1.9834x; 1.1206x over previous
//
#include <hip/hip_runtime.h>
#include <math.h>

#define SD 39
#define BLOCK 1024   // 16 waves/block, 2 blocks/CU -> 8 waves/SIMD

typedef _Float16 half8 __attribute__((ext_vector_type(8)));
typedef float f32x16 __attribute__((ext_vector_type(16)));

// ---- 32x32x16 MFMA formulation ----
// Tile = 32 batch rows; batch col = lane&31 through ALL layers (C layout:
// col=lane&31, row=(reg&3)+8*(reg>>2)+4*(lane>>5), dtype-independent).
// Slot space (h=lane>>5, j=0..7) = 16 K-slots; kappa (slot->k) is OUR choice,
// baked identically into weight frags (prologue) and data repacks (loop).
// Biases ride spare K-slots via a constant-1 data column -> C-in is a zero
// literal, no bias fragment reads at all.
// Frags (A-side, [f][64 lanes][8 halves], 1KB each):
//  f0..5  L1: f=mt*3+s, k=s*16+8h+j (k==39 -> eb1; k>39 -> 0)
//  f6..10 L2: s=f-6; s<4: o1=(r&3)+8(r>>2)+4h+32(s>>1), r=(s&1)*8+j; s==4: bias
//  f11..13 L3: s<2: o2=(r&3)+8(r>>2)+4h, r=s*8+j (m<4); s==2: bias
//  f14    D1: h==0: j<4 -> dw1[m][j], j==4 -> db1[m]
//  f15..17 D2: s<2: k1=(r&3)+8(r>>2)+4h, r=s*8+j (m<16); s==2: bias
//  f18..19 D3: s==0: k=(j&3)+8(j>>2)+4h (m<8); s==1: bias
#define NFRAG 20
#define DW_QPE (NFRAG * 256)       // dword offset of qp[0,2,4,6]
#define DW_TOT (DW_QPE + 4)        // 20.5 KB LDS

__global__ __launch_bounds__(BLOCK)
__attribute__((amdgpu_waves_per_eu(4)))
void qnet_kernel(const float* __restrict__ state,
                 const float* __restrict__ ew1, const float* __restrict__ eb1,
                 const float* __restrict__ ew2, const float* __restrict__ eb2,
                 const float* __restrict__ ew3, const float* __restrict__ eb3,
                 const float* __restrict__ qp,
                 const float* __restrict__ dw1, const float* __restrict__ db1,
                 const float* __restrict__ dw2, const float* __restrict__ db2,
                 const float* __restrict__ dw3, const float* __restrict__ db3,
                 float* __restrict__ out, long long nrows)
{
    __shared__ __align__(16) float lf[DW_TOT];
    _Float16* wh = (_Float16*)lf;
    const int tid = threadIdx.x;

    // ---- fragment build (10 iters/thread) ----
    for (int i = tid; i < NFRAG * 512; i += BLOCK) {
        int f = i >> 9, l = (i >> 3) & 63, j = i & 7;
        int h = l >> 5, m = l & 31;
        float v = 0.0f;
        if (f < 6) {                         // L1
            int mt = f / 3, s = f % 3;
            int o = mt * 32 + m, k = s * 16 + 8 * h + j;
            v = (k < SD) ? ew1[o * SD + k] : (k == SD ? eb1[o] : 0.0f);
        } else if (f < 11) {                 // L2
            int s = f - 6;
            if (s < 4) {
                int r = (s & 1) * 8 + j;
                int o1 = (r & 3) + 8 * (r >> 2) + 4 * h + 32 * (s >> 1);
                v = ew2[m * 64 + o1];
            } else v = (h == 0 && j == 0) ? eb2[m] : 0.0f;
        } else if (f < 14) {                 // L3
            int s = f - 11;
            if (s < 2) {
                int r = s * 8 + j;
                int o2 = (r & 3) + 8 * (r >> 2) + 4 * h;
                v = (m < 4) ? ew3[m * 32 + o2] : 0.0f;
            } else v = (h == 0 && j == 0 && m < 4) ? eb3[m] : 0.0f;
        } else if (f == 14) {                // D1
            v = (h == 0) ? (j < 4 ? dw1[m * 4 + j]
                                  : (j == 4 ? db1[m] : 0.0f)) : 0.0f;
        } else if (f < 18) {                 // D2
            int s = f - 15;
            if (s < 2) {
                int r = s * 8 + j;
                int k1 = (r & 3) + 8 * (r >> 2) + 4 * h;
                v = (m < 16) ? dw2[m * 32 + k1] : 0.0f;
            } else v = (h == 0 && j == 0 && m < 16) ? db2[m] : 0.0f;
        } else {                             // D3
            int s = f - 18;
            if (s == 0) {
                int k = (j & 3) + 8 * (j >> 2) + 4 * h;
                v = (m < 8) ? dw3[m * 16 + k] : 0.0f;
            } else v = (h == 0 && j == 0 && m < 8) ? db3[m] : 0.0f;
        }
        wh[i] = (_Float16)v;
    }
    for (int i = tid; i < 4; i += BLOCK) lf[DW_QPE + i] = qp[2 * i];
    __syncthreads();

    const int lane = tid & 63;
    const int h = lane >> 5, c = lane & 31;
    const long long gwave = (long long)blockIdx.x * (BLOCK / 64) + (tid >> 6);
    const long long R = gwave * 32;                    // 32 rows per wave
    if (R >= nrows) return;

    const half8* hws = (const half8*)lf;               // frag f: hws[f*64+lane]
    const float* qpep = lf + DW_QPE;

    // ---- state B-fragments: xf[s][j] = state[row=R+c][k = s*16+8h+j] ----
    const float* sp = state + (R + c) * SD;
    float4 r0 = *(const float4*)(sp + 8 * h);
    float4 r1 = *(const float4*)(sp + 8 * h + 4);
    float4 r2 = *(const float4*)(sp + 16 + 8 * h);
    float4 r3 = *(const float4*)(sp + 20 + 8 * h);
    float4 r4 = make_float4(0.f, 0.f, 0.f, 0.f);
    float4 r5 = make_float4(0.f, 0.f, 0.f, 0.f);
    if (h == 0) {                       // cols 32..38 (h=1 slots are k>=40 -> w=0)
        r4 = *(const float4*)(sp + 32);
        r5 = *(const float4*)(sp + 35); // ends exactly at col 38 (in-bounds)
    }
    half8 xf0, xf1, xf2;
    xf0[0]=(_Float16)r0.x; xf0[1]=(_Float16)r0.y; xf0[2]=(_Float16)r0.z; xf0[3]=(_Float16)r0.w;
    xf0[4]=(_Float16)r1.x; xf0[5]=(_Float16)r1.y; xf0[6]=(_Float16)r1.z; xf0[7]=(_Float16)r1.w;
    xf1[0]=(_Float16)r2.x; xf1[1]=(_Float16)r2.y; xf1[2]=(_Float16)r2.z; xf1[3]=(_Float16)r2.w;
    xf1[4]=(_Float16)r3.x; xf1[5]=(_Float16)r3.y; xf1[6]=(_Float16)r3.z; xf1[7]=(_Float16)r3.w;
    xf2[0]=(_Float16)r4.x; xf2[1]=(_Float16)r4.y; xf2[2]=(_Float16)r4.z; xf2[3]=(_Float16)r4.w;
    xf2[4]=(_Float16)r5.y; xf2[5]=(_Float16)r5.z; xf2[6]=(_Float16)r5.w;
    xf2[7]=(_Float16)1.0f;              // k=39 bias column (w=0 for h=1)

    f32x16 z;
    #pragma unroll
    for (int i = 0; i < 16; i++) z[i] = 0.0f;

    // ---- L1: two independent 32-row M-tiles, 3 K-steps ----
    f32x16 c1a = z, c1b = z;
    c1a = __builtin_amdgcn_mfma_f32_32x32x16_f16(hws[0*64+lane], xf0, c1a, 0,0,0);
    c1b = __builtin_amdgcn_mfma_f32_32x32x16_f16(hws[3*64+lane], xf0, c1b, 0,0,0);
    c1a = __builtin_amdgcn_mfma_f32_32x32x16_f16(hws[1*64+lane], xf1, c1a, 0,0,0);
    c1b = __builtin_amdgcn_mfma_f32_32x32x16_f16(hws[4*64+lane], xf1, c1b, 0,0,0);
    c1a = __builtin_amdgcn_mfma_f32_32x32x16_f16(hws[2*64+lane], xf2, c1a, 0,0,0);
    c1b = __builtin_amdgcn_mfma_f32_32x32x16_f16(hws[5*64+lane], xf2, c1b, 0,0,0);

    // relu + repack into L2 B-frags: hb[s][j] = relu(c1[mt=s>>1][(s&1)*8+j])
    half8 hb0, hb1, hb2, hb3, hbias;
    #pragma unroll
    for (int j = 0; j < 8; j++) {
        hb0[j] = (_Float16)fmaxf(c1a[j],     0.0f);
        hb1[j] = (_Float16)fmaxf(c1a[8 + j], 0.0f);
        hb2[j] = (_Float16)fmaxf(c1b[j],     0.0f);
        hb3[j] = (_Float16)fmaxf(c1b[8 + j], 0.0f);
        hbias[j] = (_Float16)0.0f;
    }
    hbias[0] = (h == 0) ? (_Float16)1.0f : (_Float16)0.0f;

    // ---- L2: 4 data steps + bias step ----
    f32x16 c2 = z;
    c2 = __builtin_amdgcn_mfma_f32_32x32x16_f16(hws[6*64+lane],  hb0,  c2, 0,0,0);
    c2 = __builtin_amdgcn_mfma_f32_32x32x16_f16(hws[7*64+lane],  hb1,  c2, 0,0,0);
    c2 = __builtin_amdgcn_mfma_f32_32x32x16_f16(hws[8*64+lane],  hb2,  c2, 0,0,0);
    c2 = __builtin_amdgcn_mfma_f32_32x32x16_f16(hws[9*64+lane],  hb3,  c2, 0,0,0);
    c2 = __builtin_amdgcn_mfma_f32_32x32x16_f16(hws[10*64+lane], hbias, c2, 0,0,0);

    half8 h30, h31;
    #pragma unroll
    for (int j = 0; j < 8; j++) {
        h30[j] = (_Float16)fmaxf(c2[j],     0.0f);
        h31[j] = (_Float16)fmaxf(c2[8 + j], 0.0f);
    }

    // ---- L3: 2 data steps + bias ----
    f32x16 e = z;
    e = __builtin_amdgcn_mfma_f32_32x32x16_f16(hws[11*64+lane], h30,  e, 0,0,0);
    e = __builtin_amdgcn_mfma_f32_32x32x16_f16(hws[12*64+lane], h31,  e, 0,0,0);
    e = __builtin_amdgcn_mfma_f32_32x32x16_f16(hws[13*64+lane], hbias, e, 0,0,0);

    // ---- quantum: ev_i = prod_{j<=i} cos(tanh(e_j)*pi + qp[2j]) ----
    // enc rows 0..3 live in h==0 lanes, regs 0..3 (h==1: e==0, harmless).
    float ev[4]; float cp = 1.0f;
    #pragma unroll
    for (int r = 0; r < 4; r++) {
        float ex = __expf(2.0f * e[r]);
        float t = 1.0f - 2.0f / (ex + 1.0f);      // tanh
        cp *= __cosf(fmaf(t, 3.14159265358979323846f, qpep[r]));
        ev[r] = cp;
    }
    half8 evf;
    #pragma unroll
    for (int j = 0; j < 8; j++) evf[j] = (_Float16)0.0f;
    if (h == 0) {
        evf[0] = (_Float16)ev[0]; evf[1] = (_Float16)ev[1];
        evf[2] = (_Float16)ev[2]; evf[3] = (_Float16)ev[3];
        evf[4] = (_Float16)1.0f;                  // db1 slot
    }

    // ---- D1: single MFMA (K-slots 0..4 of h==0) ----
    f32x16 cd1 = __builtin_amdgcn_mfma_f32_32x32x16_f16(hws[14*64+lane], evf, z, 0,0,0);
    half8 hd0, hd1;
    #pragma unroll
    for (int j = 0; j < 8; j++) {
        hd0[j] = (_Float16)fmaxf(cd1[j],     0.0f);
        hd1[j] = (_Float16)fmaxf(cd1[8 + j], 0.0f);
    }

    // ---- D2: 2 data steps + bias ----
    f32x16 cd2 = z;
    cd2 = __builtin_amdgcn_mfma_f32_32x32x16_f16(hws[15*64+lane], hd0,  cd2, 0,0,0);
    cd2 = __builtin_amdgcn_mfma_f32_32x32x16_f16(hws[16*64+lane], hd1,  cd2, 0,0,0);
    cd2 = __builtin_amdgcn_mfma_f32_32x32x16_f16(hws[17*64+lane], hbias, cd2, 0,0,0);

    half8 hd3;
    #pragma unroll
    for (int j = 0; j < 8; j++) hd3[j] = (_Float16)fmaxf(cd2[j], 0.0f);

    // ---- D3: 1 data step + bias; rows 0..7 -> regs 0..3 at dims 4h+0..3 ----
    f32x16 o = z;
    o = __builtin_amdgcn_mfma_f32_32x32x16_f16(hws[18*64+lane], hd3,  o, 0,0,0);
    o = __builtin_amdgcn_mfma_f32_32x32x16_f16(hws[19*64+lane], hbias, o, 0,0,0);

    float4* op = (float4*)(out + (R + c) * 8 + 4 * h);   // full-wave store
    *op = make_float4(o[0], o[1], o[2], o[3]);
}

extern "C" void kernel_launch(void* const* d_in, const int* in_sizes, int n_in,
                              void* d_out, int out_size, void* d_ws, size_t ws_size,
                              hipStream_t stream) {
    const float* state = (const float*)d_in[0];
    const float* ew1 = (const float*)d_in[1];
    const float* eb1 = (const float*)d_in[2];
    const float* ew2 = (const float*)d_in[3];
    const float* eb2 = (const float*)d_in[4];
    const float* ew3 = (const float*)d_in[5];
    const float* eb3 = (const float*)d_in[6];
    const float* qp  = (const float*)d_in[7];
    const float* dw1 = (const float*)d_in[8];
    const float* db1 = (const float*)d_in[9];
    const float* dw2 = (const float*)d_in[10];
    const float* db2 = (const float*)d_in[11];
    const float* dw3 = (const float*)d_in[12];
    const float* db3 = (const float*)d_in[13];
    float* out = (float*)d_out;

    const long long B = in_sizes[0] / SD;              // 262144
    // 8192 waves x 32 rows = 262144; 512 blocks x 16 waves, 2 blocks/CU.
    const int blocks = (int)((B / 32 + (BLOCK / 64) - 1) / (BLOCK / 64));
    hipLaunchKernelGGL(qnet_kernel, dim3(blocks), dim3(BLOCK), 0, stream,
                       state, ew1, eb1, ew2, eb2, ew3, eb3, qp,
                       dw1, db1, dw2, db2, dw3, db3, out, B);
}